// Round 3
// baseline (132.459 us; speedup 1.0000x reference)
//
#include <hip/hip_runtime.h>
#include <hip/hip_bf16.h>
#include <stdint.h>

using f32x4  = __attribute__((ext_vector_type(4))) float;
using f32x16 = __attribute__((ext_vector_type(16))) float;
using bf16x8 = __attribute__((ext_vector_type(8))) short;

constexpr int BATCH = 4;
constexpr int LQ_   = 256;
constexpr int LK_   = 50000;
constexpr int OUTD  = 256;
constexpr int EIN   = 128;
constexpr int KB    = 64;                     // k-rows per tile
constexpr int NKB   = (LK_ + KB - 1) / KB;    // 782
constexpr int BPB   = 64;                     // blocks per batch (grid = 256)

__device__ __forceinline__ ushort f2bf(float f) {
  uint32_t u = __builtin_bit_cast(uint32_t, f);
  u = (u + 0x7fffu + ((u >> 16) & 1u)) >> 16;
  return (ushort)u;
}
__device__ __forceinline__ short bfr(float f) {
  __hip_bfloat16 h = __float2bfloat16(f);
  return __builtin_bit_cast(short, h);
}

// ---- prep_all: blocks 0-63 -> Gn, 64-95 -> cast Wv, 96 -> zero num/den ----
__global__ __launch_bounds__(256) void prep_all(
    const float* __restrict__ query, const float* __restrict__ Wq,
    const float* __restrict__ bq,    const float* __restrict__ Wk,
    const float* __restrict__ Wv,    ushort* __restrict__ Gn,
    ushort* __restrict__ Wvbf,       float* __restrict__ numden)
{
  const int blk = blockIdx.x, tid = threadIdx.x;
  if (blk >= 64) {
    if (blk < 96) {                       // cast Wv -> bf16 (32 blocks x 2048)
      int base = (blk - 64) * 2048 + tid * 8;
      float4 a = *(const float4*)(Wv + base);
      float4 c = *(const float4*)(Wv + base + 4);
      uint4 pk;
      pk.x = (uint32_t)f2bf(a.x) | ((uint32_t)f2bf(a.y) << 16);
      pk.y = (uint32_t)f2bf(a.z) | ((uint32_t)f2bf(a.w) << 16);
      pk.z = (uint32_t)f2bf(c.x) | ((uint32_t)f2bf(c.y) << 16);
      pk.w = (uint32_t)f2bf(c.z) | ((uint32_t)f2bf(c.w) << 16);
      *(uint4*)(Wvbf + base) = pk;
    } else {                              // zero the atomic accumulators
      for (int i = tid; i < 2 * BATCH * OUTD; i += 256) numden[i] = 0.f;
    }
    return;
  }
  // ---- Gn[b] = (1/16)*(query[b]@Wq^T + bq)@Wk, 16 q-rows per block -------
  __shared__ float qin[16 * EIN];    // 8 KB
  __shared__ float Qr [16 * OUTD];   // 16 KB
  const int b = blk >> 4, q0 = (blk & 15) * 16;
  {
    int idx = tid * 8;
    int row = idx >> 7, c = idx & 127;
    const float* p = query + ((size_t)b * LQ_ + q0 + row) * EIN + c;
    float4 a = *(const float4*)p;
    float4 d = *(const float4*)(p + 4);
    float* q = &qin[row * EIN + c];
    q[0]=a.x; q[1]=a.y; q[2]=a.z; q[3]=a.w; q[4]=d.x; q[5]=d.y; q[6]=d.z; q[7]=d.w;
  }
  __syncthreads();

  float acc[16];
  {
    float bias = bq[tid];
#pragma unroll
    for (int i = 0; i < 16; ++i) acc[i] = bias;
  }
  for (int d4 = 0; d4 < EIN / 4; ++d4) {
    f32x4 w4 = *(const f32x4*)(Wq + tid * EIN + d4 * 4);
#pragma unroll
    for (int i = 0; i < 16; ++i) {
      f32x4 q4 = *(const f32x4*)(qin + i * EIN + d4 * 4);
      acc[i] += q4[0]*w4[0] + q4[1]*w4[1] + q4[2]*w4[2] + q4[3]*w4[3];
    }
  }
#pragma unroll
  for (int i = 0; i < 16; ++i) Qr[i * OUTD + tid] = acc[i];
  __syncthreads();

  float acc2[16];
#pragma unroll
  for (int i = 0; i < 16; ++i) acc2[i] = 0.f;
  for (int d4 = 0; d4 < OUTD / 4; ++d4) {
    float w0 = Wk[(d4*4+0) * OUTD + tid];
    float w1 = Wk[(d4*4+1) * OUTD + tid];
    float w2 = Wk[(d4*4+2) * OUTD + tid];
    float w3 = Wk[(d4*4+3) * OUTD + tid];
#pragma unroll
    for (int i = 0; i < 16; ++i) {
      f32x4 q4 = *(const f32x4*)(Qr + i * OUTD + d4 * 4);
      acc2[i] += q4[0]*w0 + q4[1]*w1 + q4[2]*w2 + q4[3]*w3;
    }
  }
  const float norm = 0.0625f;
#pragma unroll
  for (int i = 0; i < 16; ++i)
    Gn[((size_t)b * LQ_ + q0 + i) * OUTD + tid] = f2bf(acc2[i] * norm);
}

// ---- main ------------------------------------------------------------------
// 256 blocks (1/CU), 512 thr (8 waves). Wave w owns q-rows [w*32, w*32+32).
// LDS tile layout is FEATURE-MAJOR: 16B granule (fb, row) at fb*1024 + row*16.
//  - stage:  chunk c==fb: dest = base + c*1024 (+lane*16 by HW); global src =
//            row (t*64+lane), 16B at feature block c  -> linear LDS dest.
//  - B-read: 32 lanes read 32 different rows at same fb -> stride-16B linear
//            ds_read_b128 -> conflict-free by construction.
__global__ __launch_bounds__(512, 2) void attn_main(
    const float*  __restrict__ input, const ushort* __restrict__ Gn,
    const ushort* __restrict__ Wvbf,  float* __restrict__ num,
    float* __restrict__ den)
{
  __shared__ float ldsf[2 * 16384];   // 128 KB
  const int b = blockIdx.x >> 6, blk = blockIdx.x & (BPB - 1);
  const int t0 = (blk * NKB) >> 6, t1 = ((blk + 1) * NKB) >> 6;
  const int tid = threadIdx.x, w = tid >> 6, l = tid & 63;
  const float* src = input + (size_t)b * LK_ * 256;

  // persistent A fragments (Gn for S-gemm, Wv for V-gemm), 16 K-steps each
  const int arow = w * 32 + (l & 31);
  const ushort* gp = Gn   + ((size_t)b * LQ_ + arow) * 256 + (l >> 5) * 8;
  const ushort* vp = Wvbf + (size_t)arow * 256 + (l >> 5) * 8;
  bf16x8 ga[16], wa[16];
#pragma unroll
  for (int k = 0; k < 16; ++k) {
    ga[k] = *(const bf16x8*)(gp + k * 16);
    wa[k] = *(const bf16x8*)(vp + k * 16);
  }

  float numr[16], denr[16];
#pragma unroll
  for (int r = 0; r < 16; ++r) { numr[r] = 0.f; denr[r] = 0.f; }

  auto stage = [&](int t, int buf) {
    int rg = t * KB + l;
    rg = rg < LK_ ? rg : LK_ - 1;          // clamp (masked in epilogue)
    const float* g0 = src + (size_t)rg * 256;
    char* base = (char*)ldsf + buf * 65536;
#pragma unroll
    for (int i = 0; i < 8; ++i) {
      int c = w * 8 + i;                    // fb chunk, uniform per wave
      __builtin_amdgcn_global_load_lds(
          (const __attribute__((address_space(1))) void*)(g0 + c * 4),
          (__attribute__((address_space(3))) void*)(base + c * 1024), 16, 0, 0);
    }
  };

  stage(t0, 0);
  __syncthreads();

  for (int t = t0; t < t1; ++t) {
    const int p = (t - t0) & 1;
    if (t + 1 < t1) stage(t + 1, p ^ 1);
    const char* base = (const char*)ldsf + p * 65536;
    const char* rbase = base + (l >> 5) * 2048 + (l & 31) * 16;

#pragma unroll 1
    for (int ct = 0; ct < 2; ++ct) {
      f32x16 aS = {0,0,0,0,0,0,0,0,0,0,0,0,0,0,0,0};
      f32x16 aV = {0,0,0,0,0,0,0,0,0,0,0,0,0,0,0,0};
      const char* rb = rbase + ct * 512;
#pragma unroll
      for (int ks = 0; ks < 16; ++ks) {
        f32x4 x0 = *(const f32x4*)(rb + ks * 4096);
        f32x4 x1 = *(const f32x4*)(rb + ks * 4096 + 1024);
        bf16x8 bb;
        bb[0] = bfr(x0[0]); bb[1] = bfr(x0[1]); bb[2] = bfr(x0[2]); bb[3] = bfr(x0[3]);
        bb[4] = bfr(x1[0]); bb[5] = bfr(x1[1]); bb[6] = bfr(x1[2]); bb[7] = bfr(x1[3]);
        aS = __builtin_amdgcn_mfma_f32_32x32x16_bf16(ga[ks], bb, aS, 0, 0, 0);
        aV = __builtin_amdgcn_mfma_f32_32x32x16_bf16(wa[ks], bb, aV, 0, 0, 0);
      }
      const int krow = t * KB + ct * 32 + (l & 31);
      const bool valid = krow < LK_;
#pragma unroll
      for (int r = 0; r < 16; ++r) {
        float e = valid ? __expf(aS[r]) : 0.f;
        denr[r] += e;
        numr[r] += e * aV[r];
      }
    }
    __syncthreads();   // drains stage loads (vmcnt0) + guards buffer swap
  }

  // reduce over the 32 k-columns, then one atomic per (q, {num,den})
#pragma unroll
  for (int r = 0; r < 16; ++r) {
    float d_ = denr[r], n_ = numr[r];
#pragma unroll
    for (int m = 1; m < 32; m <<= 1) {
      d_ += __shfl_xor(d_, m, 64);
      n_ += __shfl_xor(n_, m, 64);
    }
    if ((l & 31) == 0) {
      int q = w * 32 + (r & 3) + 8 * (r >> 2) + 4 * (l >> 5);
      atomicAdd(&den[b * OUTD + q], d_);
      atomicAdd(&num[b * OUTD + q], n_);
    }
  }
}

// ---- finalize: out = num/den + bv ------------------------------------------
__global__ __launch_bounds__(256) void finalize(const float* __restrict__ num,
                                                const float* __restrict__ den,
                                                const float* __restrict__ bv,
                                                float* __restrict__ out) {
  int i = blockIdx.x * 256 + threadIdx.x;
  out[i] = num[i] / den[i] + bv[i & 255];
}

extern "C" void kernel_launch(void* const* d_in, const int* in_sizes, int n_in,
                              void* d_out, int out_size, void* d_ws, size_t ws_size,
                              hipStream_t stream)
{
  const float* query = (const float*)d_in[0];
  const float* input = (const float*)d_in[1];
  const float* Wq    = (const float*)d_in[2];
  const float* bq    = (const float*)d_in[3];
  const float* Wk    = (const float*)d_in[4];
  // d_in[5] = bk : softmax-invariant, unused
  const float* Wv    = (const float*)d_in[6];
  const float* bv    = (const float*)d_in[7];
  float* out = (float*)d_out;

  char* ws = (char*)d_ws;
  ushort* Gn     = (ushort*)ws;                       // 512 KB
  ushort* Wvbf   = (ushort*)(ws + 524288);            // 128 KB
  float*  numden = (float*)(ws + 524288 + 131072);    // 8 KB
  float*  num    = numden;
  float*  den    = numden + BATCH * OUTD;

  prep_all<<<97, 256, 0, stream>>>(query, Wq, bq, Wk, Wv, Gn, Wvbf, numden);
  attn_main<<<BATCH * BPB, 512, 0, stream>>>(input, Gn, Wvbf, num, den);
  finalize<<<BATCH, 256, 0, stream>>>(num, den, bv, out);
}

// Round 4
// 118.596 us; speedup vs baseline: 1.1169x; 1.1169x over previous
//
#include <hip/hip_runtime.h>
#include <hip/hip_bf16.h>
#include <stdint.h>

using f32x4  = __attribute__((ext_vector_type(4))) float;
using f32x16 = __attribute__((ext_vector_type(16))) float;
using bf16x8 = __attribute__((ext_vector_type(8))) short;

constexpr int BATCH = 4;
constexpr int LQ_   = 256;
constexpr int LK_   = 50000;
constexpr int OUTD  = 256;
constexpr int EIN   = 128;
constexpr int KB    = 64;                     // k-rows per tile
constexpr int NKB   = (LK_ + KB - 1) / KB;    // 782
constexpr int BPB   = 64;                     // blocks per batch (grid = 256)

__device__ __forceinline__ uint32_t f2bf(float f) {
  uint32_t u = __builtin_bit_cast(uint32_t, f);
  u = (u + 0x7fffu + ((u >> 16) & 1u)) >> 16;
  return u;
}

// ---- prep_all: blocks 0-63 -> Gn, 64-95 -> cast Wv, 96 -> zero num/den ----
__global__ __launch_bounds__(256) void prep_all(
    const float* __restrict__ query, const float* __restrict__ Wq,
    const float* __restrict__ bq,    const float* __restrict__ Wk,
    const float* __restrict__ Wv,    ushort* __restrict__ Gn,
    ushort* __restrict__ Wvbf,       float* __restrict__ numden)
{
  const int blk = blockIdx.x, tid = threadIdx.x;
  if (blk >= 64) {
    if (blk < 96) {                       // cast Wv -> bf16 (32 blocks x 2048)
      int base = (blk - 64) * 2048 + tid * 8;
      float4 a = *(const float4*)(Wv + base);
      float4 c = *(const float4*)(Wv + base + 4);
      uint4 pk;
      pk.x = f2bf(a.x) | (f2bf(a.y) << 16);
      pk.y = f2bf(a.z) | (f2bf(a.w) << 16);
      pk.z = f2bf(c.x) | (f2bf(c.y) << 16);
      pk.w = f2bf(c.z) | (f2bf(c.w) << 16);
      *(uint4*)(Wvbf + base) = pk;
    } else {                              // zero the atomic accumulators
      for (int i = tid; i < 2 * BATCH * OUTD; i += 256) numden[i] = 0.f;
    }
    return;
  }
  // ---- Gn[b] = (1/16)*(query[b]@Wq^T + bq)@Wk, 16 q-rows per block -------
  __shared__ float qin[16 * EIN];    // 8 KB
  __shared__ float Qr [16 * OUTD];   // 16 KB
  const int b = blk >> 4, q0 = (blk & 15) * 16;
  {
    int idx = tid * 8;
    int row = idx >> 7, c = idx & 127;
    const float* p = query + ((size_t)b * LQ_ + q0 + row) * EIN + c;
    float4 a = *(const float4*)p;
    float4 d = *(const float4*)(p + 4);
    float* q = &qin[row * EIN + c];
    q[0]=a.x; q[1]=a.y; q[2]=a.z; q[3]=a.w; q[4]=d.x; q[5]=d.y; q[6]=d.z; q[7]=d.w;
  }
  __syncthreads();

  float acc[16];
  {
    float bias = bq[tid];
#pragma unroll
    for (int i = 0; i < 16; ++i) acc[i] = bias;
  }
  for (int d4 = 0; d4 < EIN / 4; ++d4) {
    f32x4 w4 = *(const f32x4*)(Wq + tid * EIN + d4 * 4);
#pragma unroll
    for (int i = 0; i < 16; ++i) {
      f32x4 q4 = *(const f32x4*)(qin + i * EIN + d4 * 4);
      acc[i] += q4[0]*w4[0] + q4[1]*w4[1] + q4[2]*w4[2] + q4[3]*w4[3];
    }
  }
#pragma unroll
  for (int i = 0; i < 16; ++i) Qr[i * OUTD + tid] = acc[i];
  __syncthreads();

  float acc2[16];
#pragma unroll
  for (int i = 0; i < 16; ++i) acc2[i] = 0.f;
  for (int d4 = 0; d4 < OUTD / 4; ++d4) {
    float w0 = Wk[(d4*4+0) * OUTD + tid];
    float w1 = Wk[(d4*4+1) * OUTD + tid];
    float w2 = Wk[(d4*4+2) * OUTD + tid];
    float w3 = Wk[(d4*4+3) * OUTD + tid];
#pragma unroll
    for (int i = 0; i < 16; ++i) {
      f32x4 q4 = *(const f32x4*)(Qr + i * OUTD + d4 * 4);
      acc2[i] += q4[0]*w0 + q4[1]*w1 + q4[2]*w2 + q4[3]*w3;
    }
  }
  const float norm = 0.0625f;
#pragma unroll
  for (int i = 0; i < 16; ++i)
    Gn[((size_t)b * LQ_ + q0 + i) * OUTD + tid] = (ushort)f2bf(acc2[i] * norm);
}

// ---- main ------------------------------------------------------------------
// 256 blocks (1/CU), 512 thr (8 waves). Wave w owns q-rows [w*32, w*32+32).
// Staging is REG-STAGED bf16 (T14): coalesced float4 global loads (32 lanes =
// 1KB contiguous row), cvt_pk f32->bf16 in-reg, ds_write_b128 to LDS.
// LDS per buffer (32 KB bf16): granule (fb 0..31, row 0..63) at
//   fb*1024 + (row ^ (fb&7))*16   (feats fb*8..fb*8+7 of tile-row `row`)
// Reads: 32 lanes same fb, consecutive rows -> permuted-linear, conflict-free.
// Writes: lanes span fb -> XOR spreads bank quads (<=4-way on 1/8 traffic).
__global__ __launch_bounds__(512, 2) void attn_main(
    const float*  __restrict__ input, const ushort* __restrict__ Gn,
    const ushort* __restrict__ Wvbf,  float* __restrict__ num,
    float* __restrict__ den)
{
  __shared__ ushort lds[2 * 16384];   // 2 x 32 KB bf16
  const int b = blockIdx.x >> 6, blk = blockIdx.x & (BPB - 1);
  const int t0 = (blk * NKB) >> 6, t1 = ((blk + 1) * NKB) >> 6;
  const int tid = threadIdx.x, w = tid >> 6, l = tid & 63;
  const float* src = input + (size_t)b * LK_ * 256;

  // persistent A fragments (Gn for S-gemm, Wv for V-gemm), 16 K-steps each
  const int arow = w * 32 + (l & 31);
  const int hi = l >> 5;
  const ushort* gp = Gn   + ((size_t)b * LQ_ + arow) * 256 + hi * 8;
  const ushort* vp = Wvbf + (size_t)arow * 256 + hi * 8;
  bf16x8 ga[16], wa[16];
#pragma unroll
  for (int k = 0; k < 16; ++k) {
    ga[k] = *(const bf16x8*)(gp + k * 16);
    wa[k] = *(const bf16x8*)(vp + k * 16);
  }

  float numr[16], denr[16];
#pragma unroll
  for (int r = 0; r < 16; ++r) { numr[r] = 0.f; denr[r] = 0.f; }

  // staging regs: 4 granules x 32B (granule g = i*512+tid: row=g>>5, fb=g&31)
  float4 rga[4], rgb[4];
  auto loadreg = [&](int t) {
#pragma unroll
    for (int i = 0; i < 4; ++i) {
      int g = i * 512 + tid;
      int row = t * KB + (g >> 5);
      row = row < LK_ ? row : LK_ - 1;           // clamp (masked in epilogue)
      const float* p = src + (size_t)row * 256 + (g & 31) * 8;
      rga[i] = *(const float4*)p;
      rgb[i] = *(const float4*)(p + 4);
    }
  };
  auto writebuf = [&](int buf) {
    char* base = (char*)lds + buf * 32768;
#pragma unroll
    for (int i = 0; i < 4; ++i) {
      int g = i * 512 + tid;
      int row = g >> 5, fb = g & 31;
      uint4 pk;
      pk.x = f2bf(rga[i].x) | (f2bf(rga[i].y) << 16);
      pk.y = f2bf(rga[i].z) | (f2bf(rga[i].w) << 16);
      pk.z = f2bf(rgb[i].x) | (f2bf(rgb[i].y) << 16);
      pk.w = f2bf(rgb[i].z) | (f2bf(rgb[i].w) << 16);
      *(uint4*)(base + fb * 1024 + ((row ^ (fb & 7)) * 16)) = pk;
    }
  };

  loadreg(t0);
  writebuf(0);
  if (t0 + 1 < t1) loadreg(t0 + 1);
  __syncthreads();

  for (int t = t0; t < t1; ++t) {
    const int p = (t - t0) & 1;
    if (t + 1 < t1) {
      writebuf(p ^ 1);                 // consumes regs of tile t+1
      if (t + 2 < t1) loadreg(t + 2);  // issue next loads (in flight past sync)
    }
    const char* base = (const char*)lds + p * 32768;

#pragma unroll 1
    for (int ct = 0; ct < 2; ++ct) {
      f32x16 aS = {0,0,0,0,0,0,0,0,0,0,0,0,0,0,0,0};
      f32x16 aV = {0,0,0,0,0,0,0,0,0,0,0,0,0,0,0,0};
      const int r = ct * 32 + (l & 31);
#pragma unroll
      for (int ks = 0; ks < 16; ++ks) {
        const int fb = ks * 2 + hi;
        bf16x8 bb = *(const bf16x8*)(base + fb * 1024 + ((r ^ (fb & 7)) * 16));
        aS = __builtin_amdgcn_mfma_f32_32x32x16_bf16(ga[ks], bb, aS, 0, 0, 0);
        aV = __builtin_amdgcn_mfma_f32_32x32x16_bf16(wa[ks], bb, aV, 0, 0, 0);
      }
      const int krow = t * KB + r;
      const bool valid = krow < LK_;
#pragma unroll
      for (int rr = 0; rr < 16; ++rr) {
        float e = valid ? __expf(aS[rr]) : 0.f;
        denr[rr] += e;
        numr[rr] += e * aV[rr];
      }
    }
    __syncthreads();
  }

  // reduce over the 32 k-columns, then one atomic per (q, {num,den})
#pragma unroll
  for (int r = 0; r < 16; ++r) {
    float d_ = denr[r], n_ = numr[r];
#pragma unroll
    for (int m = 1; m < 32; m <<= 1) {
      d_ += __shfl_xor(d_, m, 64);
      n_ += __shfl_xor(n_, m, 64);
    }
    if ((l & 31) == 0) {
      int q = w * 32 + (r & 3) + 8 * (r >> 2) + 4 * hi;
      atomicAdd(&den[b * OUTD + q], d_);
      atomicAdd(&num[b * OUTD + q], n_);
    }
  }
}

// ---- finalize: out = num/den + bv ------------------------------------------
__global__ __launch_bounds__(256) void finalize(const float* __restrict__ num,
                                                const float* __restrict__ den,
                                                const float* __restrict__ bv,
                                                float* __restrict__ out) {
  int i = blockIdx.x * 256 + threadIdx.x;
  out[i] = num[i] / den[i] + bv[i & 255];
}

extern "C" void kernel_launch(void* const* d_in, const int* in_sizes, int n_in,
                              void* d_out, int out_size, void* d_ws, size_t ws_size,
                              hipStream_t stream)
{
  const float* query = (const float*)d_in[0];
  const float* input = (const float*)d_in[1];
  const float* Wq    = (const float*)d_in[2];
  const float* bq    = (const float*)d_in[3];
  const float* Wk    = (const float*)d_in[4];
  // d_in[5] = bk : softmax-invariant, unused
  const float* Wv    = (const float*)d_in[6];
  const float* bv    = (const float*)d_in[7];
  float* out = (float*)d_out;

  char* ws = (char*)d_ws;
  ushort* Gn     = (ushort*)ws;                       // 512 KB
  ushort* Wvbf   = (ushort*)(ws + 524288);            // 128 KB
  float*  numden = (float*)(ws + 524288 + 131072);    // 8 KB
  float*  num    = numden;
  float*  den    = numden + BATCH * OUTD;

  prep_all<<<97, 256, 0, stream>>>(query, Wq, bq, Wk, Wv, Gn, Wvbf, numden);
  attn_main<<<BATCH * BPB, 512, 0, stream>>>(input, Gn, Wvbf, num, den);
  finalize<<<BATCH, 256, 0, stream>>>(num, den, bv, out);
}